// Round 1
// baseline (492.690 us; speedup 1.0000x reference)
//
#include <hip/hip_runtime.h>
#include <hip/hip_bf16.h>
#include <cstdint>
#include <cstddef>

typedef __attribute__((ext_vector_type(4))) float f32x4;
typedef __attribute__((ext_vector_type(8))) short short8;
typedef __attribute__((ext_vector_type(4))) unsigned short u16x4;

static constexpr int NEDGE = 1600000;
static constexpr int NNODE = 50000;
static constexpr int MPAD  = 50048;   // 391*128
static constexpr float AVG_LOG_F = 3.4295121912749508f;

// ---- workspace layout (bytes) ----
static constexpr size_t CNT_OFF = 0;          // 50000 i32
static constexpr size_t CUR_OFF = 200000;     // 50000 i32 (contiguous with cnt for one zero pass)
static constexpr size_t RS_OFF  = 400000;     // 50001 i32
static constexpr size_t BS_OFF  = 600064;     // 32 i32
static constexpr size_t CSR_OFF = 600192;     // 1600000 i32
static constexpr size_t LDF_OFF = 7000192;    // 50000 f32
static constexpr size_t AF_OFF  = 7200192;    // 50000 f32
static constexpr size_t BT_OFF  = 7400192;    // 384*512 bf16 (row-major [ncol][k])
static constexpr size_t A_OFF   = 7793408;    // MPAD*512 bf16
static constexpr size_t C_OFF   = 59042560;   // 50000*384 f32

__device__ __forceinline__ unsigned short f2bf(float f){
  union { __hip_bfloat16 h; unsigned short u; } cv;
  cv.h = __float2bfloat16(f);
  return cv.u;
}

__global__ void k_zero(int* __restrict__ p, int n){
  int i = blockIdx.x * 256 + threadIdx.x;
  if (i < n) p[i] = 0;
}

__global__ void k_hist(const int* __restrict__ idx, int* __restrict__ cnt){
  int e = blockIdx.x * 256 + threadIdx.x;
  if (e < NEDGE) atomicAdd(&cnt[idx[e]], 1);
}

__global__ void k_scan1(const int* __restrict__ cnt, int* __restrict__ rs, int* __restrict__ bs){
  __shared__ int lds[256];
  int t = threadIdx.x;
  int base = blockIdx.x * 2048 + t * 8;
  int v[8]; int s = 0;
  #pragma unroll
  for (int j = 0; j < 8; ++j){
    int i = base + j;
    int val = (i < NNODE) ? cnt[i] : 0;
    v[j] = val; s += val;
  }
  lds[t] = s;
  __syncthreads();
  for (int off = 1; off < 256; off <<= 1){
    int add = (t >= off) ? lds[t - off] : 0;
    __syncthreads();
    lds[t] += add;
    __syncthreads();
  }
  int run = lds[t] - s;   // exclusive prefix for this thread
  #pragma unroll
  for (int j = 0; j < 8; ++j){
    int i = base + j;
    if (i < NNODE) rs[i] = run;
    run += v[j];
  }
  if (t == 255) bs[blockIdx.x] = lds[255];
}

__global__ void k_scan2(int* __restrict__ bs){
  if (threadIdx.x == 0){
    int run = 0;
    for (int i = 0; i < 25; ++i){ int v = bs[i]; bs[i] = run; run += v; }
  }
}

__global__ void k_scan3(int* __restrict__ rs, const int* __restrict__ bs){
  int i = blockIdx.x * 256 + threadIdx.x;
  if (i < NNODE) rs[i] += bs[i >> 11];
  if (i == 0) rs[NNODE] = NEDGE;
}

__global__ void k_scatter(const int* __restrict__ idx, const int* __restrict__ rs,
                          int* __restrict__ cur, int* __restrict__ csr){
  int e = blockIdx.x * 256 + threadIdx.x;
  if (e < NEDGE){
    int n = idx[e];
    int p = atomicAdd(&cur[n], 1);
    csr[rs[n] + p] = e;
  }
}

// Bt[ncol][k]: ncol = s*128 + b*32 + l ; k = t*128 + p*32 + f
// Bt = sum_i rule[i,p,b] * W[i, s*128+t*32+f, l]
__global__ void k_buildB(const float* __restrict__ rule, const float* __restrict__ W,
                         unsigned short* __restrict__ Bt){
  int id = blockIdx.x * 256 + threadIdx.x;
  if (id >= 384 * 512) return;
  int k    = id & 511;
  int ncol = id >> 9;
  int t  = k >> 7;      int xf = k & 127;
  int p  = xf >> 5;     int f  = xf & 31;
  int s  = ncol >> 7;   int j  = ncol & 127;
  int bb = j >> 5;      int l  = j & 31;
  int kw = s * 128 + t * 32 + f;
  float acc = 0.f;
  #pragma unroll
  for (int i = 0; i < 4; ++i)
    acc += rule[i * 16 + p * 4 + bb] * W[(i * 384 + kw) * 32 + l];
  Bt[(size_t)ncol * 512 + k] = f2bf(acc);
}

// one wave per node: gather edges via CSR, compute mean/min/max/std per feature
__global__ __launch_bounds__(256) void k_stats(const float* __restrict__ x,
                const int* __restrict__ csr, const int* __restrict__ rs,
                unsigned short* __restrict__ A, float* __restrict__ ldf, float* __restrict__ af){
  int wid  = blockIdx.x * 4 + (threadIdx.x >> 6);
  int lane = threadIdx.x & 63;
  if (wid >= NNODE) return;
  int s0 = rs[wid], s1 = rs[wid + 1];
  int deg = s1 - s0;
  int sub = lane >> 5;          // which edge of the pair
  int fl  = (lane & 31) * 4;    // feature offset (4 floats)
  f32x4 sum = {0.f,0.f,0.f,0.f}, ssq = {0.f,0.f,0.f,0.f};
  float inf = __builtin_inff();
  f32x4 mn = {inf,inf,inf,inf}, mx = {-inf,-inf,-inf,-inf};
  for (int base = s0; base < s1; base += 64){
    int m = min(64, s1 - base);
    int myE = (lane < m) ? csr[base + lane] : 0;
    int pairs = (m + 1) >> 1;
    #pragma unroll 2
    for (int j = 0; j < pairs; ++j){
      int sl = j * 2 + sub;
      int ed = __shfl(myE, sl);
      f32x4 v = *(const f32x4*)(x + (size_t)ed * 128 + fl);
      if (sl < m){
        sum += v;
        ssq += v * v;
        #pragma unroll
        for (int c = 0; c < 4; ++c){ mn[c] = fminf(mn[c], v[c]); mx[c] = fmaxf(mx[c], v[c]); }
      }
    }
  }
  // merge the two half-wave partials (lane i <-> i^32 hold same features)
  #pragma unroll
  for (int c = 0; c < 4; ++c){
    sum[c] += __shfl_xor(sum[c], 32);
    ssq[c] += __shfl_xor(ssq[c], 32);
    mn[c]  = fminf(mn[c], __shfl_xor(mn[c], 32));
    mx[c]  = fmaxf(mx[c], __shfl_xor(mx[c], 32));
  }
  if (lane < 32){
    float invd = (deg > 0) ? (1.0f / (float)deg) : 1.0f;
    unsigned short* Arow = A + (size_t)wid * 512;
    u16x4 stv[4];
    #pragma unroll
    for (int c = 0; c < 4; ++c){
      float mean = sum[c] * invd;
      float var  = ssq[c] * invd - mean * mean;
      float sd   = sqrtf(fmaxf(var, 0.f) + 1e-5f);
      float lo   = (deg > 0) ? mn[c] : 0.f;
      float hi   = (deg > 0) ? mx[c] : 0.f;
      stv[0][c] = f2bf(mean);
      stv[1][c] = f2bf(lo);
      stv[2][c] = f2bf(hi);
      stv[3][c] = f2bf(sd);
    }
    #pragma unroll
    for (int t = 0; t < 4; ++t)
      *(u16x4*)(Arow + t * 128 + fl) = stv[t];
  }
  if (lane == 0){
    float ld = logf((float)deg + 1.0f);
    ldf[wid] = ld / AVG_LOG_F;
    af[wid]  = (deg == 0) ? 1.0f : (AVG_LOG_F / ld);
  }
}

// C[n][s*128+j] = sum_k A[n][k] * Bt[s*128+j][k]    (bf16 MFMA, fp32 acc)
// grid: (3 n-tiles, 391 m-tiles); block 256 = 4 waves in 2x2; wave tile 64x64
__global__ __launch_bounds__(256) void k_gemm(const unsigned short* __restrict__ A,
                                              const unsigned short* __restrict__ Bt,
                                              float* __restrict__ C){
  int w = threadIdx.x >> 6, lane = threadIdx.x & 63;
  int wr = w >> 1, wc = w & 1;
  int m0 = blockIdx.y * 128 + wr * 64;
  int n0 = blockIdx.x * 128 + wc * 64;
  int r16 = lane & 15, kq = lane >> 4;
  f32x4 acc[4][4];
  #pragma unroll
  for (int m = 0; m < 4; ++m)
    #pragma unroll
    for (int n = 0; n < 4; ++n) acc[m][n] = (f32x4){0.f,0.f,0.f,0.f};
  const unsigned short* Ab = A  + (size_t)(m0 + r16) * 512 + kq * 8;
  const unsigned short* Bb = Bt + (size_t)(n0 + r16) * 512 + kq * 8;
  for (int kk = 0; kk < 512; kk += 32){
    short8 a[4], b[4];
    #pragma unroll
    for (int m = 0; m < 4; ++m) a[m] = *(const short8*)(Ab + (size_t)m * 16 * 512 + kk);
    #pragma unroll
    for (int n = 0; n < 4; ++n) b[n] = *(const short8*)(Bb + (size_t)n * 16 * 512 + kk);
    #pragma unroll
    for (int m = 0; m < 4; ++m)
      #pragma unroll
      for (int n = 0; n < 4; ++n)
        acc[m][n] = __builtin_amdgcn_mfma_f32_16x16x32_bf16(a[m], b[n], acc[m][n], 0, 0, 0);
  }
  int rq = lane >> 4;
  #pragma unroll
  for (int m = 0; m < 4; ++m){
    int row0 = m0 + m * 16 + rq * 4;
    #pragma unroll
    for (int n = 0; n < 4; ++n){
      int col = n0 + n * 16 + r16;
      #pragma unroll
      for (int r = 0; r < 4; ++r){
        int row = row0 + r;
        if (row < NNODE) C[(size_t)row * 384 + col] = acc[m][n][r];
      }
    }
  }
}

__global__ void k_combine(const float* __restrict__ C, const float* __restrict__ ldf,
                          const float* __restrict__ af, const float* __restrict__ bias,
                          float* __restrict__ out){
  int id = blockIdx.x * 256 + threadIdx.x;   // one float4 each; 50000*32 total
  if (id >= NNODE * 32) return;
  int n  = id >> 5;
  int j4 = (id & 31) * 4;
  const float* Crow = C + (size_t)n * 384;
  f32x4 c0 = *(const f32x4*)(Crow + j4);
  f32x4 c1 = *(const f32x4*)(Crow + 128 + j4);
  f32x4 c2 = *(const f32x4*)(Crow + 256 + j4);
  f32x4 bb = *(const f32x4*)(bias + j4);
  float l = ldf[n], a = af[n];
  f32x4 r = c0 + l * c1 + a * c2 + bb;
  *(f32x4*)(out + (size_t)n * 128 + j4) = r;
}

extern "C" void kernel_launch(void* const* d_in, const int* in_sizes, int n_in,
                              void* d_out, int out_size, void* d_ws, size_t ws_size,
                              hipStream_t stream){
  const float* x    = (const float*)d_in[0];
  const int*   idx  = (const int*)d_in[1];
  const float* rule = (const float*)d_in[2];
  const float* W    = (const float*)d_in[3];
  const float* bias = (const float*)d_in[4];
  char* ws = (char*)d_ws;
  int* cnt = (int*)(ws + CNT_OFF);
  int* cur = (int*)(ws + CUR_OFF);
  int* rs  = (int*)(ws + RS_OFF);
  int* bs  = (int*)(ws + BS_OFF);
  int* csr = (int*)(ws + CSR_OFF);
  float* ldf = (float*)(ws + LDF_OFF);
  float* af  = (float*)(ws + AF_OFF);
  unsigned short* Bt   = (unsigned short*)(ws + BT_OFF);
  unsigned short* Abuf = (unsigned short*)(ws + A_OFF);
  float* Cbuf = (float*)(ws + C_OFF);
  float* out  = (float*)d_out;

  k_zero<<<dim3((100000 + 255) / 256), 256, 0, stream>>>(cnt, 100000); // cnt + cur
  k_hist<<<dim3(6250), 256, 0, stream>>>(idx, cnt);
  k_scan1<<<dim3(25), 256, 0, stream>>>(cnt, rs, bs);
  k_scan2<<<dim3(1), 64, 0, stream>>>(bs);
  k_scan3<<<dim3(196), 256, 0, stream>>>(rs, bs);
  k_scatter<<<dim3(6250), 256, 0, stream>>>(idx, rs, cur, csr);
  k_buildB<<<dim3(768), 256, 0, stream>>>(rule, W, Bt);
  k_stats<<<dim3(12500), 256, 0, stream>>>(x, csr, rs, Abuf, ldf, af);
  k_gemm<<<dim3(3, 391), 256, 0, stream>>>(Abuf, Bt, Cbuf);
  k_combine<<<dim3(6250), 256, 0, stream>>>(Cbuf, ldf, af, bias, out);
}

// Round 2
// 461.831 us; speedup vs baseline: 1.0668x; 1.0668x over previous
//
#include <hip/hip_runtime.h>
#include <hip/hip_bf16.h>
#include <cstdint>
#include <cstddef>

typedef __attribute__((ext_vector_type(4))) float f32x4;
typedef __attribute__((ext_vector_type(8))) short short8;
typedef __attribute__((ext_vector_type(4))) unsigned short u16x4;

static constexpr int NEDGE = 1600000;
static constexpr int NNODE = 50000;
static constexpr int MPAD  = 50048;   // 782*64
static constexpr float AVG_LOG_F = 3.4295121912749508f;

// ---- workspace layout (bytes) ----
static constexpr size_t CNT_OFF = 0;          // 50000 i32
static constexpr size_t CUR_OFF = 200000;     // 50000 i32
static constexpr size_t RS_OFF  = 400000;     // 50001 i32
static constexpr size_t BS_OFF  = 600064;     // 32 i32
static constexpr size_t CSR_OFF = 600192;     // 1600000 i32
static constexpr size_t LDF_OFF = 7000192;    // 50000 f32
static constexpr size_t AF_OFF  = 7200192;    // 50000 f32
static constexpr size_t BT_OFF  = 7400192;    // 384*512 bf16 (row-major [ncol][k])
static constexpr size_t A_OFF   = 7793408;    // MPAD*512 bf16

__device__ __forceinline__ unsigned short f2bf(float f){
  union { __hip_bfloat16 h; unsigned short u; } cv;
  cv.h = __float2bfloat16(f);
  return cv.u;
}

__global__ void k_zero(int* __restrict__ p, int n){
  int i = blockIdx.x * 256 + threadIdx.x;
  if (i < n) p[i] = 0;
}

__global__ void k_hist(const int* __restrict__ idx, int* __restrict__ cnt){
  int e = blockIdx.x * 256 + threadIdx.x;
  if (e < NEDGE) atomicAdd(&cnt[idx[e]], 1);
}

__global__ void k_scan1(const int* __restrict__ cnt, int* __restrict__ rs, int* __restrict__ bs){
  __shared__ int lds[256];
  int t = threadIdx.x;
  int base = blockIdx.x * 2048 + t * 8;
  int v[8]; int s = 0;
  #pragma unroll
  for (int j = 0; j < 8; ++j){
    int i = base + j;
    int val = (i < NNODE) ? cnt[i] : 0;
    v[j] = val; s += val;
  }
  lds[t] = s;
  __syncthreads();
  for (int off = 1; off < 256; off <<= 1){
    int add = (t >= off) ? lds[t - off] : 0;
    __syncthreads();
    lds[t] += add;
    __syncthreads();
  }
  int run = lds[t] - s;   // exclusive prefix for this thread
  #pragma unroll
  for (int j = 0; j < 8; ++j){
    int i = base + j;
    if (i < NNODE) rs[i] = run;
    run += v[j];
  }
  if (t == 255) bs[blockIdx.x] = lds[255];
}

__global__ void k_scan2(int* __restrict__ bs){
  if (threadIdx.x == 0){
    int run = 0;
    for (int i = 0; i < 25; ++i){ int v = bs[i]; bs[i] = run; run += v; }
  }
}

__global__ void k_scan3(int* __restrict__ rs, const int* __restrict__ bs){
  int i = blockIdx.x * 256 + threadIdx.x;
  if (i < NNODE) rs[i] += bs[i >> 11];
  if (i == 0) rs[NNODE] = NEDGE;
}

__global__ void k_scatter(const int* __restrict__ idx, const int* __restrict__ rs,
                          int* __restrict__ cur, int* __restrict__ csr){
  int e = blockIdx.x * 256 + threadIdx.x;
  if (e < NEDGE){
    int n = idx[e];
    int p = atomicAdd(&cur[n], 1);
    csr[rs[n] + p] = e;
  }
}

// Bt[ncol][k]: ncol = s*128 + b*32 + l ; k = t*128 + p*32 + f
// Bt = sum_i rule[i,p,b] * W[i, s*128+t*32+f, l]
__global__ void k_buildB(const float* __restrict__ rule, const float* __restrict__ W,
                         unsigned short* __restrict__ Bt){
  int id = blockIdx.x * 256 + threadIdx.x;
  if (id >= 384 * 512) return;
  int k    = id & 511;
  int ncol = id >> 9;
  int t  = k >> 7;      int xf = k & 127;
  int p  = xf >> 5;     int f  = xf & 31;
  int s  = ncol >> 7;   int j  = ncol & 127;
  int bb = j >> 5;      int l  = j & 31;
  int kw = s * 128 + t * 32 + f;
  float acc = 0.f;
  #pragma unroll
  for (int i = 0; i < 4; ++i)
    acc += rule[i * 16 + p * 4 + bb] * W[(i * 384 + kw) * 32 + l];
  Bt[(size_t)ncol * 512 + k] = f2bf(acc);
}

// one wave per node: gather edges via CSR, compute mean/min/max/std per feature
__global__ __launch_bounds__(256) void k_stats(const float* __restrict__ x,
                const int* __restrict__ csr, const int* __restrict__ rs,
                unsigned short* __restrict__ A, float* __restrict__ ldf, float* __restrict__ af){
  int wid  = blockIdx.x * 4 + (threadIdx.x >> 6);
  int lane = threadIdx.x & 63;
  if (wid >= NNODE) return;
  int s0 = rs[wid], s1 = rs[wid + 1];
  int deg = s1 - s0;
  int sub = lane >> 5;          // which edge of the pair
  int fl  = (lane & 31) * 4;    // feature offset (4 floats)
  f32x4 sum = {0.f,0.f,0.f,0.f}, ssq = {0.f,0.f,0.f,0.f};
  float inf = __builtin_inff();
  f32x4 mn = {inf,inf,inf,inf}, mx = {-inf,-inf,-inf,-inf};
  for (int base = s0; base < s1; base += 64){
    int m = min(64, s1 - base);
    int myE = (lane < m) ? csr[base + lane] : 0;
    int pairs = (m + 1) >> 1;
    #pragma unroll 4
    for (int j = 0; j < pairs; ++j){
      int sl = j * 2 + sub;
      int ed = __shfl(myE, sl);
      f32x4 v = *(const f32x4*)(x + (size_t)ed * 128 + fl);
      if (sl < m){
        sum += v;
        ssq += v * v;
        #pragma unroll
        for (int c = 0; c < 4; ++c){ mn[c] = fminf(mn[c], v[c]); mx[c] = fmaxf(mx[c], v[c]); }
      }
    }
  }
  // merge the two half-wave partials (lane i <-> i^32 hold same features)
  #pragma unroll
  for (int c = 0; c < 4; ++c){
    sum[c] += __shfl_xor(sum[c], 32);
    ssq[c] += __shfl_xor(ssq[c], 32);
    mn[c]  = fminf(mn[c], __shfl_xor(mn[c], 32));
    mx[c]  = fmaxf(mx[c], __shfl_xor(mx[c], 32));
  }
  if (lane < 32){
    float invd = (deg > 0) ? (1.0f / (float)deg) : 1.0f;
    unsigned short* Arow = A + (size_t)wid * 512;
    u16x4 stv[4];
    #pragma unroll
    for (int c = 0; c < 4; ++c){
      float mean = sum[c] * invd;
      float var  = ssq[c] * invd - mean * mean;
      float sd   = sqrtf(fmaxf(var, 0.f) + 1e-5f);
      float lo   = (deg > 0) ? mn[c] : 0.f;
      float hi   = (deg > 0) ? mx[c] : 0.f;
      stv[0][c] = f2bf(mean);
      stv[1][c] = f2bf(lo);
      stv[2][c] = f2bf(hi);
      stv[3][c] = f2bf(sd);
    }
    #pragma unroll
    for (int t = 0; t < 4; ++t)
      *(u16x4*)(Arow + t * 128 + fl) = stv[t];
  }
  if (lane == 0){
    float ld = logf((float)deg + 1.0f);
    ldf[wid] = ld / AVG_LOG_F;
    af[wid]  = (deg == 0) ? 1.0f : (AVG_LOG_F / ld);
  }
}

// Fused GEMM + degree-scaler combine.
// Each block: 64 rows, all 384 Bt cols; wave w owns output cols [w*32, w*32+32)
// and computes the 3 segment fragments (s*128 + col) for them, then
// out[row][col] = accS0 + ldf[row]*accS1 + af[row]*accS2 + bias[col].
__global__ __launch_bounds__(256) void k_gemm_fused(const unsigned short* __restrict__ A,
                                                    const unsigned short* __restrict__ Bt,
                                                    const float* __restrict__ ldf,
                                                    const float* __restrict__ af,
                                                    const float* __restrict__ bias,
                                                    float* __restrict__ out){
  int w = threadIdx.x >> 6, lane = threadIdx.x & 63;
  int m0 = blockIdx.x * 64;
  int j0 = w * 32;
  int r16 = lane & 15, kq = lane >> 4;
  f32x4 acc[4][2][3];   // [m-frag][col-frag][segment]
  #pragma unroll
  for (int m = 0; m < 4; ++m)
    #pragma unroll
    for (int nj = 0; nj < 2; ++nj)
      #pragma unroll
      for (int s = 0; s < 3; ++s) acc[m][nj][s] = (f32x4){0.f,0.f,0.f,0.f};
  const unsigned short* Ab = A  + (size_t)(m0 + r16) * 512 + kq * 8;
  const unsigned short* Bb = Bt + (size_t)(j0 + r16) * 512 + kq * 8;
  for (int kk = 0; kk < 512; kk += 32){
    short8 a[4];
    #pragma unroll
    for (int m = 0; m < 4; ++m) a[m] = *(const short8*)(Ab + (size_t)m * 16 * 512 + kk);
    short8 b[3][2];
    #pragma unroll
    for (int s = 0; s < 3; ++s)
      #pragma unroll
      for (int nj = 0; nj < 2; ++nj)
        b[s][nj] = *(const short8*)(Bb + (size_t)(s * 128 + nj * 16) * 512 + kk);
    #pragma unroll
    for (int m = 0; m < 4; ++m)
      #pragma unroll
      for (int nj = 0; nj < 2; ++nj)
        #pragma unroll
        for (int s = 0; s < 3; ++s)
          acc[m][nj][s] = __builtin_amdgcn_mfma_f32_16x16x32_bf16(a[m], b[s][nj], acc[m][nj][s], 0, 0, 0);
  }
  int rq = kq;
  #pragma unroll
  for (int m = 0; m < 4; ++m){
    int row0 = m0 + m * 16 + rq * 4;
    float lv[4], av[4];
    #pragma unroll
    for (int r = 0; r < 4; ++r){
      int rr = min(row0 + r, NNODE - 1);
      lv[r] = ldf[rr];
      av[r] = af[rr];
    }
    #pragma unroll
    for (int nj = 0; nj < 2; ++nj){
      int col = j0 + nj * 16 + r16;
      float bb = bias[col];
      #pragma unroll
      for (int r = 0; r < 4; ++r){
        int row = row0 + r;
        if (row < NNODE)
          out[(size_t)row * 128 + col] =
            acc[m][nj][0][r] + lv[r] * acc[m][nj][1][r] + av[r] * acc[m][nj][2][r] + bb;
      }
    }
  }
}

extern "C" void kernel_launch(void* const* d_in, const int* in_sizes, int n_in,
                              void* d_out, int out_size, void* d_ws, size_t ws_size,
                              hipStream_t stream){
  const float* x    = (const float*)d_in[0];
  const int*   idx  = (const int*)d_in[1];
  const float* rule = (const float*)d_in[2];
  const float* W    = (const float*)d_in[3];
  const float* bias = (const float*)d_in[4];
  char* ws = (char*)d_ws;
  int* cnt = (int*)(ws + CNT_OFF);
  int* cur = (int*)(ws + CUR_OFF);
  int* rs  = (int*)(ws + RS_OFF);
  int* bs  = (int*)(ws + BS_OFF);
  int* csr = (int*)(ws + CSR_OFF);
  float* ldf = (float*)(ws + LDF_OFF);
  float* af  = (float*)(ws + AF_OFF);
  unsigned short* Bt   = (unsigned short*)(ws + BT_OFF);
  unsigned short* Abuf = (unsigned short*)(ws + A_OFF);
  float* out  = (float*)d_out;

  k_zero<<<dim3((100000 + 255) / 256), 256, 0, stream>>>(cnt, 100000); // cnt + cur
  // zero A padding rows (50000..50047) so padded GEMM tiles are clean
  k_zero<<<dim3(48), 256, 0, stream>>>((int*)(Abuf + (size_t)NNODE * 512), 48 * 256);
  k_hist<<<dim3(6250), 256, 0, stream>>>(idx, cnt);
  k_scan1<<<dim3(25), 256, 0, stream>>>(cnt, rs, bs);
  k_scan2<<<dim3(1), 64, 0, stream>>>(bs);
  k_scan3<<<dim3(196), 256, 0, stream>>>(rs, bs);
  k_scatter<<<dim3(6250), 256, 0, stream>>>(idx, rs, cur, csr);
  k_buildB<<<dim3(768), 256, 0, stream>>>(rule, W, Bt);
  k_stats<<<dim3(12500), 256, 0, stream>>>(x, csr, rs, Abuf, ldf, af);
  k_gemm_fused<<<dim3(MPAD / 64), 256, 0, stream>>>(Abuf, Bt, ldf, af, bias, out);
}

// Round 3
// 379.237 us; speedup vs baseline: 1.2992x; 1.2178x over previous
//
#include <hip/hip_runtime.h>
#include <hip/hip_bf16.h>
#include <cstdint>
#include <cstddef>

typedef __attribute__((ext_vector_type(4))) float f32x4;
typedef __attribute__((ext_vector_type(8))) short short8;
typedef __attribute__((ext_vector_type(4))) unsigned short u16x4;

static constexpr int NEDGE = 1600000;
static constexpr int NNODE = 50000;
static constexpr int MPAD  = 50048;   // 782*64
static constexpr float AVG_LOG_F = 3.4295121912749508f;

// ---- workspace layout (bytes) ----
static constexpr size_t CNT_OFF  = 0;          // 50000 i32
static constexpr size_t RS_OFF   = 200000;     // 50001 i32
static constexpr size_t BS_OFF   = 400064;     // 32 i32
static constexpr size_t RANK_OFF = 400192;     // 1600000 i32
static constexpr size_t CSR_OFF  = 6800192;    // 1600000 i32
static constexpr size_t LDF_OFF  = 13200192;   // 50000 f32
static constexpr size_t AF_OFF   = 13400192;   // 50000 f32
static constexpr size_t BT_OFF   = 13600192;   // 384*512 bf16
static constexpr size_t A_OFF    = 13993408;   // MPAD*512 bf16

__device__ __forceinline__ unsigned short f2bf(float f){
  union { __hip_bfloat16 h; unsigned short u; } cv;
  cv.h = __float2bfloat16(f);
  return cv.u;
}

__global__ void k_zero(int* __restrict__ p, int n){
  int i = blockIdx.x * 256 + threadIdx.x;
  if (i < n) p[i] = 0;
}

// histogram + per-edge rank in one atomic pass
__global__ void k_hist(const int* __restrict__ idx, int* __restrict__ cnt,
                       int* __restrict__ rank){
  int e = blockIdx.x * 256 + threadIdx.x;
  if (e < NEDGE){
    int n = idx[e];
    rank[e] = atomicAdd(&cnt[n], 1);
  }
}

__global__ void k_scan1(const int* __restrict__ cnt, int* __restrict__ rs, int* __restrict__ bs){
  __shared__ int lds[256];
  int t = threadIdx.x;
  int base = blockIdx.x * 2048 + t * 8;
  int v[8]; int s = 0;
  #pragma unroll
  for (int j = 0; j < 8; ++j){
    int i = base + j;
    int val = (i < NNODE) ? cnt[i] : 0;
    v[j] = val; s += val;
  }
  lds[t] = s;
  __syncthreads();
  for (int off = 1; off < 256; off <<= 1){
    int add = (t >= off) ? lds[t - off] : 0;
    __syncthreads();
    lds[t] += add;
    __syncthreads();
  }
  int run = lds[t] - s;   // exclusive prefix for this thread
  #pragma unroll
  for (int j = 0; j < 8; ++j){
    int i = base + j;
    if (i < NNODE) rs[i] = run;
    run += v[j];
  }
  if (t == 255) bs[blockIdx.x] = lds[255];
}

__global__ void k_scan2(int* __restrict__ bs){
  if (threadIdx.x == 0){
    int run = 0;
    for (int i = 0; i < 25; ++i){ int v = bs[i]; bs[i] = run; run += v; }
  }
}

__global__ void k_scan3(int* __restrict__ rs, const int* __restrict__ bs){
  int i = blockIdx.x * 256 + threadIdx.x;
  if (i < NNODE) rs[i] += bs[i >> 11];
  if (i == 0) rs[NNODE] = NEDGE;
}

// atomic-free scatter using precomputed ranks
__global__ void k_scatter(const int* __restrict__ idx, const int* __restrict__ rank,
                          const int* __restrict__ rs, int* __restrict__ csr){
  int e = blockIdx.x * 256 + threadIdx.x;
  if (e < NEDGE){
    int n = idx[e];
    csr[rs[n] + rank[e]] = e;
  }
}

// Bt[ncol][k]: ncol = s*128 + b*32 + l ; k = t*128 + p*32 + f
// Bt = sum_i rule[i,p,b] * W[i, s*128+t*32+f, l]
__global__ void k_buildB(const float* __restrict__ rule, const float* __restrict__ W,
                         unsigned short* __restrict__ Bt){
  int id = blockIdx.x * 256 + threadIdx.x;
  if (id >= 384 * 512) return;
  int k    = id & 511;
  int ncol = id >> 9;
  int t  = k >> 7;      int xf = k & 127;
  int p  = xf >> 5;     int f  = xf & 31;
  int s  = ncol >> 7;   int j  = ncol & 127;
  int bb = j >> 5;      int l  = j & 31;
  int kw = s * 128 + t * 32 + f;
  float acc = 0.f;
  #pragma unroll
  for (int i = 0; i < 4; ++i)
    acc += rule[i * 16 + p * 4 + bb] * W[(i * 384 + kw) * 32 + l];
  Bt[(size_t)ncol * 512 + k] = f2bf(acc);
}

// one wave per node: gather edges via CSR, compute mean/min/max/std per feature
__global__ __launch_bounds__(256) void k_stats(const float* __restrict__ x,
                const int* __restrict__ csr, const int* __restrict__ rs,
                unsigned short* __restrict__ A, float* __restrict__ ldf, float* __restrict__ af){
  int wid  = blockIdx.x * 4 + (threadIdx.x >> 6);
  int lane = threadIdx.x & 63;
  if (wid >= NNODE) return;
  int s0 = rs[wid], s1 = rs[wid + 1];
  int deg = s1 - s0;
  int sub = lane >> 5;          // which edge of the pair
  int fl  = (lane & 31) * 4;    // feature offset (4 floats)
  f32x4 sum = {0.f,0.f,0.f,0.f}, ssq = {0.f,0.f,0.f,0.f};
  float inf = __builtin_inff();
  f32x4 mn = {inf,inf,inf,inf}, mx = {-inf,-inf,-inf,-inf};
  for (int base = s0; base < s1; base += 64){
    int m = min(64, s1 - base);
    int myE = (lane < m) ? csr[base + lane] : 0;
    int pairs = (m + 1) >> 1;
    #pragma unroll 8
    for (int j = 0; j < pairs; ++j){
      int sl = j * 2 + sub;
      int ed = __shfl(myE, sl);
      f32x4 v = *(const f32x4*)(x + (size_t)ed * 128 + fl);
      if (sl < m){
        sum += v;
        ssq += v * v;
        #pragma unroll
        for (int c = 0; c < 4; ++c){ mn[c] = fminf(mn[c], v[c]); mx[c] = fmaxf(mx[c], v[c]); }
      }
    }
  }
  // merge the two half-wave partials (lane i <-> i^32 hold same features)
  #pragma unroll
  for (int c = 0; c < 4; ++c){
    sum[c] += __shfl_xor(sum[c], 32);
    ssq[c] += __shfl_xor(ssq[c], 32);
    mn[c]  = fminf(mn[c], __shfl_xor(mn[c], 32));
    mx[c]  = fmaxf(mx[c], __shfl_xor(mx[c], 32));
  }
  if (lane < 32){
    float invd = (deg > 0) ? (1.0f / (float)deg) : 1.0f;
    unsigned short* Arow = A + (size_t)wid * 512;
    u16x4 stv[4];
    #pragma unroll
    for (int c = 0; c < 4; ++c){
      float mean = sum[c] * invd;
      float var  = ssq[c] * invd - mean * mean;
      float sd   = sqrtf(fmaxf(var, 0.f) + 1e-5f);
      float lo   = (deg > 0) ? mn[c] : 0.f;
      float hi   = (deg > 0) ? mx[c] : 0.f;
      stv[0][c] = f2bf(mean);
      stv[1][c] = f2bf(lo);
      stv[2][c] = f2bf(hi);
      stv[3][c] = f2bf(sd);
    }
    #pragma unroll
    for (int t = 0; t < 4; ++t)
      *(u16x4*)(Arow + t * 128 + fl) = stv[t];
  }
  if (lane == 0){
    float ld = logf((float)deg + 1.0f);
    ldf[wid] = ld / AVG_LOG_F;
    af[wid]  = (deg == 0) ? 1.0f : (AVG_LOG_F / ld);
  }
}

// Fused GEMM + degree-scaler combine.
// Each block: 64 rows, all 384 Bt cols; wave w owns output cols [w*32, w*32+32)
__global__ __launch_bounds__(256) void k_gemm_fused(const unsigned short* __restrict__ A,
                                                    const unsigned short* __restrict__ Bt,
                                                    const float* __restrict__ ldf,
                                                    const float* __restrict__ af,
                                                    const float* __restrict__ bias,
                                                    float* __restrict__ out){
  int w = threadIdx.x >> 6, lane = threadIdx.x & 63;
  int m0 = blockIdx.x * 64;
  int j0 = w * 32;
  int r16 = lane & 15, kq = lane >> 4;
  f32x4 acc[4][2][3];   // [m-frag][col-frag][segment]
  #pragma unroll
  for (int m = 0; m < 4; ++m)
    #pragma unroll
    for (int nj = 0; nj < 2; ++nj)
      #pragma unroll
      for (int s = 0; s < 3; ++s) acc[m][nj][s] = (f32x4){0.f,0.f,0.f,0.f};
  const unsigned short* Ab = A  + (size_t)(m0 + r16) * 512 + kq * 8;
  const unsigned short* Bb = Bt + (size_t)(j0 + r16) * 512 + kq * 8;
  for (int kk = 0; kk < 512; kk += 32){
    short8 a[4];
    #pragma unroll
    for (int m = 0; m < 4; ++m) a[m] = *(const short8*)(Ab + (size_t)m * 16 * 512 + kk);
    short8 b[3][2];
    #pragma unroll
    for (int s = 0; s < 3; ++s)
      #pragma unroll
      for (int nj = 0; nj < 2; ++nj)
        b[s][nj] = *(const short8*)(Bb + (size_t)(s * 128 + nj * 16) * 512 + kk);
    #pragma unroll
    for (int m = 0; m < 4; ++m)
      #pragma unroll
      for (int nj = 0; nj < 2; ++nj)
        #pragma unroll
        for (int s = 0; s < 3; ++s)
          acc[m][nj][s] = __builtin_amdgcn_mfma_f32_16x16x32_bf16(a[m], b[s][nj], acc[m][nj][s], 0, 0, 0);
  }
  int rq = kq;
  #pragma unroll
  for (int m = 0; m < 4; ++m){
    int row0 = m0 + m * 16 + rq * 4;
    float lv[4], av[4];
    #pragma unroll
    for (int r = 0; r < 4; ++r){
      int rr = min(row0 + r, NNODE - 1);
      lv[r] = ldf[rr];
      av[r] = af[rr];
    }
    #pragma unroll
    for (int nj = 0; nj < 2; ++nj){
      int col = j0 + nj * 16 + r16;
      float bb = bias[col];
      #pragma unroll
      for (int r = 0; r < 4; ++r){
        int row = row0 + r;
        if (row < NNODE)
          out[(size_t)row * 128 + col] =
            acc[m][nj][0][r] + lv[r] * acc[m][nj][1][r] + av[r] * acc[m][nj][2][r] + bb;
      }
    }
  }
}

extern "C" void kernel_launch(void* const* d_in, const int* in_sizes, int n_in,
                              void* d_out, int out_size, void* d_ws, size_t ws_size,
                              hipStream_t stream){
  const float* x    = (const float*)d_in[0];
  const int*   idx  = (const int*)d_in[1];
  const float* rule = (const float*)d_in[2];
  const float* W    = (const float*)d_in[3];
  const float* bias = (const float*)d_in[4];
  char* ws = (char*)d_ws;
  int* cnt  = (int*)(ws + CNT_OFF);
  int* rs   = (int*)(ws + RS_OFF);
  int* bs   = (int*)(ws + BS_OFF);
  int* rank = (int*)(ws + RANK_OFF);
  int* csr  = (int*)(ws + CSR_OFF);
  float* ldf = (float*)(ws + LDF_OFF);
  float* af  = (float*)(ws + AF_OFF);
  unsigned short* Bt   = (unsigned short*)(ws + BT_OFF);
  unsigned short* Abuf = (unsigned short*)(ws + A_OFF);
  float* out  = (float*)d_out;

  k_zero<<<dim3((50000 + 255) / 256), 256, 0, stream>>>(cnt, 50000);
  // zero A padding rows (50000..50047) so padded GEMM tiles are clean
  k_zero<<<dim3(48), 256, 0, stream>>>((int*)(Abuf + (size_t)NNODE * 512), 48 * 256);
  k_hist<<<dim3(6250), 256, 0, stream>>>(idx, cnt, rank);
  k_scan1<<<dim3(25), 256, 0, stream>>>(cnt, rs, bs);
  k_scan2<<<dim3(1), 64, 0, stream>>>(bs);
  k_scan3<<<dim3(196), 256, 0, stream>>>(rs, bs);
  k_scatter<<<dim3(6250), 256, 0, stream>>>(idx, rank, rs, csr);
  k_buildB<<<dim3(768), 256, 0, stream>>>(rule, W, Bt);
  k_stats<<<dim3(12500), 256, 0, stream>>>(x, csr, rs, Abuf, ldf, af);
  k_gemm_fused<<<dim3(MPAD / 64), 256, 0, stream>>>(Abuf, Bt, ldf, af, bias, out);
}

// Round 4
// 378.367 us; speedup vs baseline: 1.3021x; 1.0023x over previous
//
#include <hip/hip_runtime.h>
#include <hip/hip_bf16.h>
#include <cstdint>
#include <cstddef>

typedef __attribute__((ext_vector_type(4))) float f32x4;
typedef __attribute__((ext_vector_type(8))) short short8;
typedef __attribute__((ext_vector_type(4))) unsigned short u16x4;

static constexpr int NEDGE = 1600000;
static constexpr int NNODE = 50000;
static constexpr int MPAD  = 50048;   // 782*64
static constexpr float AVG_LOG_F = 3.4295121912749508f;

// ---- workspace layout (bytes) ----
static constexpr size_t CNT_OFF  = 0;          // 50000 i32
static constexpr size_t RS_OFF   = 200000;     // 50001 i32
static constexpr size_t BS_OFF   = 400064;     // 32 i32
static constexpr size_t RANK_OFF = 400192;     // 1600000 i32
static constexpr size_t CSR_OFF  = 6800192;    // 1600000 i32
static constexpr size_t LDF_OFF  = 13200192;   // 50000 f32
static constexpr size_t AF_OFF   = 13400192;   // 50000 f32
static constexpr size_t BT_OFF   = 13600192;   // 384*512 bf16
static constexpr size_t A_OFF    = 13993408;   // MPAD*512 bf16

__device__ __forceinline__ unsigned short f2bf(float f){
  union { __hip_bfloat16 h; unsigned short u; } cv;
  cv.h = __float2bfloat16(f);
  return cv.u;
}

// zero cnt (50000 ints) and the A padding rows (48*256 ints) in one launch
__global__ void k_zero2(int* __restrict__ cnt, int* __restrict__ apad){
  int i = blockIdx.x * 256 + threadIdx.x;
  if (i < NNODE) cnt[i] = 0;
  int j = i - NNODE;
  if (j >= 0 && j < 48 * 256) apad[j] = 0;
}

// histogram + per-edge rank, 4 edges/thread
__global__ void k_hist(const int4* __restrict__ idx4, int* __restrict__ cnt,
                       int4* __restrict__ rank4){
  int e4 = blockIdx.x * 256 + threadIdx.x;
  if (e4 < NEDGE / 4){
    int4 n = idx4[e4];
    int4 r;
    r.x = atomicAdd(&cnt[n.x], 1);
    r.y = atomicAdd(&cnt[n.y], 1);
    r.z = atomicAdd(&cnt[n.z], 1);
    r.w = atomicAdd(&cnt[n.w], 1);
    rank4[e4] = r;
  }
}

__global__ void k_scan1(const int* __restrict__ cnt, int* __restrict__ rs, int* __restrict__ bs){
  __shared__ int lds[256];
  int t = threadIdx.x;
  int base = blockIdx.x * 2048 + t * 8;
  int v[8]; int s = 0;
  #pragma unroll
  for (int j = 0; j < 8; ++j){
    int i = base + j;
    int val = (i < NNODE) ? cnt[i] : 0;
    v[j] = val; s += val;
  }
  lds[t] = s;
  __syncthreads();
  for (int off = 1; off < 256; off <<= 1){
    int add = (t >= off) ? lds[t - off] : 0;
    __syncthreads();
    lds[t] += add;
    __syncthreads();
  }
  int run = lds[t] - s;   // exclusive prefix for this thread
  #pragma unroll
  for (int j = 0; j < 8; ++j){
    int i = base + j;
    if (i < NNODE) rs[i] = run;
    run += v[j];
  }
  if (t == 255) bs[blockIdx.x] = lds[255];
}

// adds block offsets; each block locally scans the 25 block-sums
__global__ void k_scan3(int* __restrict__ rs, const int* __restrict__ bs){
  __shared__ int pref[32];
  int t = threadIdx.x;
  if (t < 32){
    int v = (t < 25) ? bs[t] : 0;
    #pragma unroll
    for (int off = 1; off < 32; off <<= 1){
      int u = __shfl_up(v, off);
      if (t >= off) v += u;
    }
    pref[t] = v;  // inclusive scan
  }
  __syncthreads();
  int i = blockIdx.x * 256 + t;
  if (i < NNODE){
    int b = i >> 11;
    int add = (b == 0) ? 0 : pref[b - 1];
    rs[i] += add;
  }
  if (i == 0) rs[NNODE] = NEDGE;
}

// atomic-free scatter, 4 edges/thread
__global__ void k_scatter(const int4* __restrict__ idx4, const int4* __restrict__ rank4,
                          const int* __restrict__ rs, int* __restrict__ csr){
  int e4 = blockIdx.x * 256 + threadIdx.x;
  if (e4 < NEDGE / 4){
    int4 n = idx4[e4];
    int4 r = rank4[e4];
    int e = e4 * 4;
    csr[rs[n.x] + r.x] = e + 0;
    csr[rs[n.y] + r.y] = e + 1;
    csr[rs[n.z] + r.z] = e + 2;
    csr[rs[n.w] + r.w] = e + 3;
  }
}

// Bt[ncol][k]: ncol = s*128 + b*32 + l ; k = t*128 + p*32 + f
// Bt = sum_i rule[i,p,b] * W[i, s*128+t*32+f, l]
__global__ void k_buildB(const float* __restrict__ rule, const float* __restrict__ W,
                         unsigned short* __restrict__ Bt){
  int id = blockIdx.x * 256 + threadIdx.x;
  if (id >= 384 * 512) return;
  int k    = id & 511;
  int ncol = id >> 9;
  int t  = k >> 7;      int xf = k & 127;
  int p  = xf >> 5;     int f  = xf & 31;
  int s  = ncol >> 7;   int j  = ncol & 127;
  int bb = j >> 5;      int l  = j & 31;
  int kw = s * 128 + t * 32 + f;
  float acc = 0.f;
  #pragma unroll
  for (int i = 0; i < 4; ++i)
    acc += rule[i * 16 + p * 4 + bb] * W[(i * 384 + kw) * 32 + l];
  Bt[(size_t)ncol * 512 + k] = f2bf(acc);
}

// one wave per node: gather edges via CSR, compute mean/min/max/std per feature
__global__ __launch_bounds__(256) void k_stats(const float* __restrict__ x,
                const int* __restrict__ csr, const int* __restrict__ rs,
                unsigned short* __restrict__ A, float* __restrict__ ldf, float* __restrict__ af){
  int wid  = blockIdx.x * 4 + (threadIdx.x >> 6);
  int lane = threadIdx.x & 63;
  if (wid >= NNODE) return;
  int s0 = rs[wid], s1 = rs[wid + 1];
  int deg = s1 - s0;
  int sub = lane >> 5;          // which edge of the pair
  int fl  = (lane & 31) * 4;    // feature offset (4 floats)
  f32x4 sum = {0.f,0.f,0.f,0.f}, ssq = {0.f,0.f,0.f,0.f};
  float inf = __builtin_inff();
  f32x4 mn = {inf,inf,inf,inf}, mx = {-inf,-inf,-inf,-inf};
  for (int base = s0; base < s1; base += 64){
    int m = min(64, s1 - base);
    int myE = (lane < m) ? csr[base + lane] : 0;
    int pairs = (m + 1) >> 1;
    #pragma unroll 16
    for (int j = 0; j < pairs; ++j){
      int sl = j * 2 + sub;
      int ed = __shfl(myE, sl);
      f32x4 v = *(const f32x4*)(x + (size_t)ed * 128 + fl);
      if (sl < m){
        sum += v;
        ssq += v * v;
        #pragma unroll
        for (int c = 0; c < 4; ++c){ mn[c] = fminf(mn[c], v[c]); mx[c] = fmaxf(mx[c], v[c]); }
      }
    }
  }
  // merge the two half-wave partials (lane i <-> i^32 hold same features)
  #pragma unroll
  for (int c = 0; c < 4; ++c){
    sum[c] += __shfl_xor(sum[c], 32);
    ssq[c] += __shfl_xor(ssq[c], 32);
    mn[c]  = fminf(mn[c], __shfl_xor(mn[c], 32));
    mx[c]  = fmaxf(mx[c], __shfl_xor(mx[c], 32));
  }
  if (lane < 32){
    float invd = (deg > 0) ? (1.0f / (float)deg) : 1.0f;
    unsigned short* Arow = A + (size_t)wid * 512;
    u16x4 stv[4];
    #pragma unroll
    for (int c = 0; c < 4; ++c){
      float mean = sum[c] * invd;
      float var  = ssq[c] * invd - mean * mean;
      float sd   = sqrtf(fmaxf(var, 0.f) + 1e-5f);
      float lo   = (deg > 0) ? mn[c] : 0.f;
      float hi   = (deg > 0) ? mx[c] : 0.f;
      stv[0][c] = f2bf(mean);
      stv[1][c] = f2bf(lo);
      stv[2][c] = f2bf(hi);
      stv[3][c] = f2bf(sd);
    }
    #pragma unroll
    for (int t = 0; t < 4; ++t)
      *(u16x4*)(Arow + t * 128 + fl) = stv[t];
  }
  if (lane == 0){
    float ld = logf((float)deg + 1.0f);
    ldf[wid] = ld / AVG_LOG_F;
    af[wid]  = (deg == 0) ? 1.0f : (AVG_LOG_F / ld);
  }
}

// Fused GEMM + degree-scaler combine.
// Each block: 64 rows, all 384 Bt cols; wave w owns output cols [w*32, w*32+32)
__global__ __launch_bounds__(256) void k_gemm_fused(const unsigned short* __restrict__ A,
                                                    const unsigned short* __restrict__ Bt,
                                                    const float* __restrict__ ldf,
                                                    const float* __restrict__ af,
                                                    const float* __restrict__ bias,
                                                    float* __restrict__ out){
  int w = threadIdx.x >> 6, lane = threadIdx.x & 63;
  int m0 = blockIdx.x * 64;
  int j0 = w * 32;
  int r16 = lane & 15, kq = lane >> 4;
  f32x4 acc[4][2][3];   // [m-frag][col-frag][segment]
  #pragma unroll
  for (int m = 0; m < 4; ++m)
    #pragma unroll
    for (int nj = 0; nj < 2; ++nj)
      #pragma unroll
      for (int s = 0; s < 3; ++s) acc[m][nj][s] = (f32x4){0.f,0.f,0.f,0.f};
  const unsigned short* Ab = A  + (size_t)(m0 + r16) * 512 + kq * 8;
  const unsigned short* Bb = Bt + (size_t)(j0 + r16) * 512 + kq * 8;
  for (int kk = 0; kk < 512; kk += 32){
    short8 a[4];
    #pragma unroll
    for (int m = 0; m < 4; ++m) a[m] = *(const short8*)(Ab + (size_t)m * 16 * 512 + kk);
    short8 b[3][2];
    #pragma unroll
    for (int s = 0; s < 3; ++s)
      #pragma unroll
      for (int nj = 0; nj < 2; ++nj)
        b[s][nj] = *(const short8*)(Bb + (size_t)(s * 128 + nj * 16) * 512 + kk);
    #pragma unroll
    for (int m = 0; m < 4; ++m)
      #pragma unroll
      for (int nj = 0; nj < 2; ++nj)
        #pragma unroll
        for (int s = 0; s < 3; ++s)
          acc[m][nj][s] = __builtin_amdgcn_mfma_f32_16x16x32_bf16(a[m], b[s][nj], acc[m][nj][s], 0, 0, 0);
  }
  int rq = kq;
  #pragma unroll
  for (int m = 0; m < 4; ++m){
    int row0 = m0 + m * 16 + rq * 4;
    float lv[4], av[4];
    #pragma unroll
    for (int r = 0; r < 4; ++r){
      int rr = min(row0 + r, NNODE - 1);
      lv[r] = ldf[rr];
      av[r] = af[rr];
    }
    #pragma unroll
    for (int nj = 0; nj < 2; ++nj){
      int col = j0 + nj * 16 + r16;
      float bb = bias[col];
      #pragma unroll
      for (int r = 0; r < 4; ++r){
        int row = row0 + r;
        if (row < NNODE)
          out[(size_t)row * 128 + col] =
            acc[m][nj][0][r] + lv[r] * acc[m][nj][1][r] + av[r] * acc[m][nj][2][r] + bb;
      }
    }
  }
}

extern "C" void kernel_launch(void* const* d_in, const int* in_sizes, int n_in,
                              void* d_out, int out_size, void* d_ws, size_t ws_size,
                              hipStream_t stream){
  const float* x    = (const float*)d_in[0];
  const int*   idx  = (const int*)d_in[1];
  const float* rule = (const float*)d_in[2];
  const float* W    = (const float*)d_in[3];
  const float* bias = (const float*)d_in[4];
  char* ws = (char*)d_ws;
  int* cnt  = (int*)(ws + CNT_OFF);
  int* rs   = (int*)(ws + RS_OFF);
  int* bs   = (int*)(ws + BS_OFF);
  int* rank = (int*)(ws + RANK_OFF);
  int* csr  = (int*)(ws + CSR_OFF);
  float* ldf = (float*)(ws + LDF_OFF);
  float* af  = (float*)(ws + AF_OFF);
  unsigned short* Bt   = (unsigned short*)(ws + BT_OFF);
  unsigned short* Abuf = (unsigned short*)(ws + A_OFF);
  float* out  = (float*)d_out;

  k_zero2<<<dim3((NNODE + 48 * 256 + 255) / 256), 256, 0, stream>>>(
      cnt, (int*)(Abuf + (size_t)NNODE * 512));
  k_hist<<<dim3((NEDGE / 4 + 255) / 256), 256, 0, stream>>>((const int4*)idx, cnt, (int4*)rank);
  k_scan1<<<dim3(25), 256, 0, stream>>>(cnt, rs, bs);
  k_scan3<<<dim3(196), 256, 0, stream>>>(rs, bs);
  k_scatter<<<dim3((NEDGE / 4 + 255) / 256), 256, 0, stream>>>(
      (const int4*)idx, (const int4*)rank, rs, csr);
  k_buildB<<<dim3(768), 256, 0, stream>>>(rule, W, Bt);
  k_stats<<<dim3(12500), 256, 0, stream>>>(x, csr, rs, Abuf, ldf, af);
  k_gemm_fused<<<dim3(MPAD / 64), 256, 0, stream>>>(Abuf, Bt, ldf, af, bias, out);
}

// Round 5
// 339.581 us; speedup vs baseline: 1.4509x; 1.1142x over previous
//
#include <hip/hip_runtime.h>
#include <hip/hip_bf16.h>
#include <cstdint>
#include <cstddef>

typedef __attribute__((ext_vector_type(4))) float f32x4;
typedef __attribute__((ext_vector_type(8))) short short8;
typedef __attribute__((ext_vector_type(4))) unsigned short u16x4;

static constexpr int NEDGE = 1600000;
static constexpr int NNODE = 50000;
static constexpr int MPAD  = 50048;   // 782*64
static constexpr float AVG_LOG_F = 3.4295121912749508f;

// ---- workspace layout (bytes) ----
static constexpr size_t CNT_OFF  = 0;          // 50000 i32
static constexpr size_t RS_OFF   = 200000;     // 50001 i32
static constexpr size_t BS_OFF   = 400064;     // 32 i32
static constexpr size_t RANK_OFF = 400192;     // 1600000 i32
static constexpr size_t CSR_OFF  = 6800192;    // 1600000 i32
static constexpr size_t LDF_OFF  = 13200192;   // 50000 f32
static constexpr size_t AF_OFF   = 13400192;   // 50000 f32
static constexpr size_t BT_OFF   = 13600192;   // 384*512 bf16
static constexpr size_t A_OFF    = 13993408;   // MPAD*512 bf16

__device__ __forceinline__ unsigned short f2bf(float f){
  union { __hip_bfloat16 h; unsigned short u; } cv;
  cv.h = __float2bfloat16(f);
  return cv.u;
}

// zero cnt (50000 ints) and the A padding rows (48*256 ints) in one launch
__global__ void k_zero2(int* __restrict__ cnt, int* __restrict__ apad){
  int i = blockIdx.x * 256 + threadIdx.x;
  if (i < NNODE) cnt[i] = 0;
  int j = i - NNODE;
  if (j >= 0 && j < 48 * 256) apad[j] = 0;
}

// histogram + per-edge rank, 4 edges/thread
__global__ void k_hist(const int4* __restrict__ idx4, int* __restrict__ cnt,
                       int4* __restrict__ rank4){
  int e4 = blockIdx.x * 256 + threadIdx.x;
  if (e4 < NEDGE / 4){
    int4 n = idx4[e4];
    int4 r;
    r.x = atomicAdd(&cnt[n.x], 1);
    r.y = atomicAdd(&cnt[n.y], 1);
    r.z = atomicAdd(&cnt[n.z], 1);
    r.w = atomicAdd(&cnt[n.w], 1);
    rank4[e4] = r;
  }
}

__global__ void k_scan1(const int* __restrict__ cnt, int* __restrict__ rs, int* __restrict__ bs){
  __shared__ int lds[256];
  int t = threadIdx.x;
  int base = blockIdx.x * 2048 + t * 8;
  int v[8]; int s = 0;
  #pragma unroll
  for (int j = 0; j < 8; ++j){
    int i = base + j;
    int val = (i < NNODE) ? cnt[i] : 0;
    v[j] = val; s += val;
  }
  lds[t] = s;
  __syncthreads();
  for (int off = 1; off < 256; off <<= 1){
    int add = (t >= off) ? lds[t - off] : 0;
    __syncthreads();
    lds[t] += add;
    __syncthreads();
  }
  int run = lds[t] - s;   // exclusive prefix for this thread
  #pragma unroll
  for (int j = 0; j < 8; ++j){
    int i = base + j;
    if (i < NNODE) rs[i] = run;
    run += v[j];
  }
  if (t == 255) bs[blockIdx.x] = lds[255];
}

// adds block offsets; each block locally scans the 25 block-sums
__global__ void k_scan3(int* __restrict__ rs, const int* __restrict__ bs){
  __shared__ int pref[32];
  int t = threadIdx.x;
  if (t < 32){
    int v = (t < 25) ? bs[t] : 0;
    #pragma unroll
    for (int off = 1; off < 32; off <<= 1){
      int u = __shfl_up(v, off);
      if (t >= off) v += u;
    }
    pref[t] = v;  // inclusive scan
  }
  __syncthreads();
  int i = blockIdx.x * 256 + t;
  if (i < NNODE){
    int b = i >> 11;
    int add = (b == 0) ? 0 : pref[b - 1];
    rs[i] += add;
  }
  if (i == 0) rs[NNODE] = NEDGE;
}

// atomic-free scatter, 4 edges/thread
__global__ void k_scatter(const int4* __restrict__ idx4, const int4* __restrict__ rank4,
                          const int* __restrict__ rs, int* __restrict__ csr){
  int e4 = blockIdx.x * 256 + threadIdx.x;
  if (e4 < NEDGE / 4){
    int4 n = idx4[e4];
    int4 r = rank4[e4];
    int e = e4 * 4;
    csr[rs[n.x] + r.x] = e + 0;
    csr[rs[n.y] + r.y] = e + 1;
    csr[rs[n.z] + r.z] = e + 2;
    csr[rs[n.w] + r.w] = e + 3;
  }
}

// Bt[ncol][k]: ncol = s*128 + b*32 + l ; k = t*128 + p*32 + f
// Bt = sum_i rule[i,p,b] * W[i, s*128+t*32+f, l]
__global__ void k_buildB(const float* __restrict__ rule, const float* __restrict__ W,
                         unsigned short* __restrict__ Bt){
  int id = blockIdx.x * 256 + threadIdx.x;
  if (id >= 384 * 512) return;
  int k    = id & 511;
  int ncol = id >> 9;
  int t  = k >> 7;      int xf = k & 127;
  int p  = xf >> 5;     int f  = xf & 31;
  int s  = ncol >> 7;   int j  = ncol & 127;
  int bb = j >> 5;      int l  = j & 31;
  int kw = s * 128 + t * 32 + f;
  float acc = 0.f;
  #pragma unroll
  for (int i = 0; i < 4; ++i)
    acc += rule[i * 16 + p * 4 + bb] * W[(i * 384 + kw) * 32 + l];
  Bt[(size_t)ncol * 512 + k] = f2bf(acc);
}

// one wave per node: gather edges via CSR, compute mean/min/max/std per feature
__global__ __launch_bounds__(256) void k_stats(const float* __restrict__ x,
                const int* __restrict__ csr, const int* __restrict__ rs,
                unsigned short* __restrict__ A, float* __restrict__ ldf, float* __restrict__ af){
  int wid  = blockIdx.x * 4 + (threadIdx.x >> 6);
  int lane = threadIdx.x & 63;
  if (wid >= NNODE) return;
  int s0 = rs[wid], s1 = rs[wid + 1];
  int deg = s1 - s0;
  int sub = lane >> 5;          // which edge of the pair
  int fl  = (lane & 31) * 4;    // feature offset (4 floats)
  f32x4 sum = {0.f,0.f,0.f,0.f}, ssq = {0.f,0.f,0.f,0.f};
  float inf = __builtin_inff();
  f32x4 mn = {inf,inf,inf,inf}, mx = {-inf,-inf,-inf,-inf};
  for (int base = s0; base < s1; base += 64){
    int m = min(64, s1 - base);
    int myE = (lane < m) ? csr[base + lane] : 0;
    int pairs = (m + 1) >> 1;
    #pragma unroll 16
    for (int j = 0; j < pairs; ++j){
      int sl = j * 2 + sub;
      int ed = __shfl(myE, sl);
      // x rows are read exactly once -> keep them out of L2 (non-temporal)
      f32x4 v = __builtin_nontemporal_load((const f32x4*)(x + (size_t)ed * 128 + fl));
      if (sl < m){
        sum += v;
        ssq += v * v;
        #pragma unroll
        for (int c = 0; c < 4; ++c){ mn[c] = fminf(mn[c], v[c]); mx[c] = fmaxf(mx[c], v[c]); }
      }
    }
  }
  // merge the two half-wave partials (lane i <-> i^32 hold same features)
  #pragma unroll
  for (int c = 0; c < 4; ++c){
    sum[c] += __shfl_xor(sum[c], 32);
    ssq[c] += __shfl_xor(ssq[c], 32);
    mn[c]  = fminf(mn[c], __shfl_xor(mn[c], 32));
    mx[c]  = fmaxf(mx[c], __shfl_xor(mx[c], 32));
  }
  if (lane < 32){
    float invd = (deg > 0) ? (1.0f / (float)deg) : 1.0f;
    unsigned short* Arow = A + (size_t)wid * 512;
    u16x4 stv[4];
    #pragma unroll
    for (int c = 0; c < 4; ++c){
      float mean = sum[c] * invd;
      float var  = ssq[c] * invd - mean * mean;
      float sd   = sqrtf(fmaxf(var, 0.f) + 1e-5f);
      float lo   = (deg > 0) ? mn[c] : 0.f;
      float hi   = (deg > 0) ? mx[c] : 0.f;
      stv[0][c] = f2bf(mean);
      stv[1][c] = f2bf(lo);
      stv[2][c] = f2bf(hi);
      stv[3][c] = f2bf(sd);
    }
    #pragma unroll
    for (int t = 0; t < 4; ++t)
      *(u16x4*)(Arow + t * 128 + fl) = stv[t];
  }
  if (lane == 0){
    float ld = logf((float)deg + 1.0f);
    ldf[wid] = ld / AVG_LOG_F;
    af[wid]  = (deg == 0) ? 1.0f : (AVG_LOG_F / ld);
  }
}

// Fused GEMM + degree-scaler combine.
// A-tile (64 rows x 512 k) staged once per block in LDS (was loaded 4x, once
// per wave). Row stride padded to 520 halves (1040 B) so ds_read_b128 over
// 16 rows lands 2 lanes/bank (free). B stays direct (waves read disjoint cols).
__global__ __launch_bounds__(256) void k_gemm_fused(const unsigned short* __restrict__ A,
                                                    const unsigned short* __restrict__ Bt,
                                                    const float* __restrict__ ldf,
                                                    const float* __restrict__ af,
                                                    const float* __restrict__ bias,
                                                    float* __restrict__ out){
  __shared__ unsigned short Alds[64 * 520];   // 66560 B
  int w = threadIdx.x >> 6, lane = threadIdx.x & 63;
  int m0 = blockIdx.x * 64;
  int j0 = w * 32;
  int r16 = lane & 15, kq = lane >> 4;
  // stage A: 256 threads x 16B x 16 iters = 64 KB, coalesced
  {
    const unsigned short* src = A + (size_t)m0 * 512;
    int t = threadIdx.x;
    #pragma unroll
    for (int i = 0; i < 16; ++i){
      int off8 = (i * 256 + t) * 8;          // element offset, linear in source
      int r = off8 >> 9, c = off8 & 511;
      short8 v = *(const short8*)(src + off8);
      *(short8*)(&Alds[r * 520 + c]) = v;
    }
  }
  __syncthreads();
  f32x4 acc[4][2][3];   // [m-frag][col-frag][segment]
  #pragma unroll
  for (int m = 0; m < 4; ++m)
    #pragma unroll
    for (int nj = 0; nj < 2; ++nj)
      #pragma unroll
      for (int s = 0; s < 3; ++s) acc[m][nj][s] = (f32x4){0.f,0.f,0.f,0.f};
  const unsigned short* Bb = Bt + (size_t)(j0 + r16) * 512 + kq * 8;
  const unsigned short* Al = Alds + (size_t)r16 * 520 + kq * 8;
  for (int kk = 0; kk < 512; kk += 32){
    short8 a[4];
    #pragma unroll
    for (int m = 0; m < 4; ++m) a[m] = *(const short8*)(Al + m * 16 * 520 + kk);
    short8 b[3][2];
    #pragma unroll
    for (int s = 0; s < 3; ++s)
      #pragma unroll
      for (int nj = 0; nj < 2; ++nj)
        b[s][nj] = *(const short8*)(Bb + (size_t)(s * 128 + nj * 16) * 512 + kk);
    #pragma unroll
    for (int m = 0; m < 4; ++m)
      #pragma unroll
      for (int nj = 0; nj < 2; ++nj)
        #pragma unroll
        for (int s = 0; s < 3; ++s)
          acc[m][nj][s] = __builtin_amdgcn_mfma_f32_16x16x32_bf16(a[m], b[s][nj], acc[m][nj][s], 0, 0, 0);
  }
  int rq = kq;
  #pragma unroll
  for (int m = 0; m < 4; ++m){
    int row0 = m0 + m * 16 + rq * 4;
    float lv[4], av[4];
    #pragma unroll
    for (int r = 0; r < 4; ++r){
      int rr = min(row0 + r, NNODE - 1);
      lv[r] = ldf[rr];
      av[r] = af[rr];
    }
    #pragma unroll
    for (int nj = 0; nj < 2; ++nj){
      int col = j0 + nj * 16 + r16;
      float bb = bias[col];
      #pragma unroll
      for (int r = 0; r < 4; ++r){
        int row = row0 + r;
        if (row < NNODE)
          out[(size_t)row * 128 + col] =
            acc[m][nj][0][r] + lv[r] * acc[m][nj][1][r] + av[r] * acc[m][nj][2][r] + bb;
      }
    }
  }
}

extern "C" void kernel_launch(void* const* d_in, const int* in_sizes, int n_in,
                              void* d_out, int out_size, void* d_ws, size_t ws_size,
                              hipStream_t stream){
  const float* x    = (const float*)d_in[0];
  const int*   idx  = (const int*)d_in[1];
  const float* rule = (const float*)d_in[2];
  const float* W    = (const float*)d_in[3];
  const float* bias = (const float*)d_in[4];
  char* ws = (char*)d_ws;
  int* cnt  = (int*)(ws + CNT_OFF);
  int* rs   = (int*)(ws + RS_OFF);
  int* bs   = (int*)(ws + BS_OFF);
  int* rank = (int*)(ws + RANK_OFF);
  int* csr  = (int*)(ws + CSR_OFF);
  float* ldf = (float*)(ws + LDF_OFF);
  float* af  = (float*)(ws + AF_OFF);
  unsigned short* Bt   = (unsigned short*)(ws + BT_OFF);
  unsigned short* Abuf = (unsigned short*)(ws + A_OFF);
  float* out  = (float*)d_out;

  k_buildB<<<dim3(768), 256, 0, stream>>>(rule, W, Bt);   // independent: first
  k_zero2<<<dim3((NNODE + 48 * 256 + 255) / 256), 256, 0, stream>>>(
      cnt, (int*)(Abuf + (size_t)NNODE * 512));
  k_hist<<<dim3((NEDGE / 4 + 255) / 256), 256, 0, stream>>>((const int4*)idx, cnt, (int4*)rank);
  k_scan1<<<dim3(25), 256, 0, stream>>>(cnt, rs, bs);
  k_scan3<<<dim3(196), 256, 0, stream>>>(rs, bs);
  k_scatter<<<dim3((NEDGE / 4 + 255) / 256), 256, 0, stream>>>(
      (const int4*)idx, (const int4*)rank, rs, csr);
  k_stats<<<dim3(12500), 256, 0, stream>>>(x, csr, rs, Abuf, ldf, af);
  k_gemm_fused<<<dim3(MPAD / 64), 256, 0, stream>>>(Abuf, Bt, ldf, af, bias, out);
}